// Round 1
// baseline (443.713 us; speedup 1.0000x reference)
//
#include <hip/hip_runtime.h>

// ---------- types ----------
typedef __attribute__((ext_vector_type(8))) short bf16x8;   // 8 bf16 in 4 VGPRs
typedef __attribute__((ext_vector_type(4))) float f32x4;    // MFMA C/D

__device__ __forceinline__ unsigned short f2bf(float f) {
  unsigned int u = __float_as_uint(f);
  u += 0x7fffu + ((u >> 16) & 1u);      // round-to-nearest-even
  return (unsigned short)(u >> 16);
}

// async global->LDS, 16B per lane; LDS dest = wave-uniform base + lane*16
__device__ __forceinline__ void cp16(const unsigned short* g, unsigned short* l) {
  __builtin_amdgcn_global_load_lds((const __attribute__((address_space(1))) void*)g,
                                   (__attribute__((address_space(3))) void*)l, 16, 0, 0);
}

// ---------- fp32 -> bf16 elementwise (float4 loads) ----------
__global__ void conv_bf16(const float* __restrict__ in, unsigned short* __restrict__ out, int n4) {
  int i = blockIdx.x * blockDim.x + threadIdx.x;
  if (i < n4) {
    float4 v = ((const float4*)in)[i];
    ushort4 o;
    o.x = f2bf(v.x); o.y = f2bf(v.y); o.z = f2bf(v.z); o.w = f2bf(v.w);
    ((ushort4*)out)[i] = o;
  }
}

// ---------- 1024x1024 transpose + convert: WT[n][k] = bf16(W[k][n]) ----------
__global__ void transpose_conv(const float* __restrict__ W, unsigned short* __restrict__ WT) {
  __shared__ float t[32][33];
  int bx = blockIdx.x * 32, by = blockIdx.y * 32;
  int x = threadIdx.x, y0 = threadIdx.y;
#pragma unroll
  for (int r = 0; r < 4; ++r)
    t[y0 + r * 8][x] = W[(size_t)(by + y0 + r * 8) * 1024 + bx + x];
  __syncthreads();
#pragma unroll
  for (int r = 0; r < 4; ++r)
    WT[(size_t)(bx + y0 + r * 8) * 1024 + by + x] = f2bf(t[x][y0 + r * 8]);
}

// ---------- bf16 GEMM, C[M][N] = A[M][K] * B^T  (B stored [N][K]) ----------
// m97 structure: 128x128 tile, BK=32, global_load_lds width 16, 16x16x32 MFMA.
// Writes bf16 to Cb if non-null, else fp32 to Cf. scale applied in epilogue.
__global__ __launch_bounds__(256) void gemm_bt(
    const unsigned short* __restrict__ A, const unsigned short* __restrict__ B,
    float* __restrict__ Cf, unsigned short* __restrict__ Cb,
    int M, int N, int K, float scale)
{
  __shared__ __attribute__((aligned(16))) unsigned short lds[8192]; // A [128][32] @0, B [128][32] @4096
  int w = threadIdx.x >> 6, lane = threadIdx.x & 63;
  int lh = lane & 15, q4 = lane >> 4;
  int tm = blockIdx.y * 128, tn = blockIdx.x * 128;
  int wm = (w & 1) * 64, wn = (w >> 1) * 64;

  f32x4 acc[4][4] = {};

  for (int k0 = 0; k0 < K; k0 += 32) {
#pragma unroll
    for (int i = 0; i < 2; ++i) {
      int c = w * 2 + i;
      int o = c * 1024 + lane * 16;            // byte offset within 8KB tile
      int row = o >> 6;                        // 64B per row (32 bf16)
      int colu = (o & 63) >> 1;                // ushort col
      cp16(A + (size_t)(tm + row) * K + k0 + colu, lds + c * 512);
      cp16(B + (size_t)(tn + row) * K + k0 + colu, lds + 4096 + c * 512);
    }
    __syncthreads();
    bf16x8 afr[4], bfr[4];
#pragma unroll
    for (int r = 0; r < 4; ++r)
      afr[r] = *(const bf16x8*)(lds + (wm + r * 16 + lh) * 32 + q4 * 8);
#pragma unroll
    for (int c = 0; c < 4; ++c)
      bfr[c] = *(const bf16x8*)(lds + 4096 + (wn + c * 16 + lh) * 32 + q4 * 8);
#pragma unroll
    for (int r = 0; r < 4; ++r)
#pragma unroll
      for (int c = 0; c < 4; ++c)
        acc[r][c] = __builtin_amdgcn_mfma_f32_16x16x32_bf16(afr[r], bfr[c], acc[r][c], 0, 0, 0);
    __syncthreads();
  }

  // epilogue: C/D layout col=lane&15, row=(lane>>4)*4+reg  [m89/m91 verified]
  if (Cb) {
#pragma unroll
    for (int r = 0; r < 4; ++r)
#pragma unroll
      for (int c = 0; c < 4; ++c)
#pragma unroll
        for (int e = 0; e < 4; ++e) {
          int row = tm + wm + r * 16 + q4 * 4 + e;
          int col = tn + wn + c * 16 + lh;
          Cb[(size_t)row * N + col] = f2bf(acc[r][c][e] * scale);
        }
  } else {
#pragma unroll
    for (int r = 0; r < 4; ++r)
#pragma unroll
      for (int c = 0; c < 4; ++c)
#pragma unroll
        for (int e = 0; e < 4; ++e) {
          int row = tm + wm + r * 16 + q4 * 4 + e;
          int col = tn + wn + c * 16 + lh;
          Cf[(size_t)row * N + col] = acc[r][c][e] * scale;
        }
  }
}

// ---------- flash attention ----------
// Q: [B*512][1024] bf16 (pre-scaled by 1/8), Kp: [B*4096][1024] bf16,
// VT: [1024][B*4096] bf16, bias: [B][4096] fp32, O: [B*512][1024] bf16.
// Block: 256 thr = 4 waves; Q-tile 64 rows (16/wave); K-tiles of 64 tokens.
__global__ __launch_bounds__(256) void attn_kernel(
    const unsigned short* __restrict__ Q, const unsigned short* __restrict__ Kp,
    const unsigned short* __restrict__ VT, const float* __restrict__ bias,
    unsigned short* __restrict__ O)
{
  // K tile [2][64][32] @0, VT tile [2][64][32] @4096, P strips @8192 (+w*1024, [2][16][32])
  __shared__ __attribute__((aligned(16))) unsigned short lds[12288];
  int w = threadIdx.x >> 6, lane = threadIdx.x & 63;
  int lh = lane & 15, q4 = lane >> 4;
  int b = blockIdx.y >> 4, h = blockIdx.y & 15;
  int q0 = blockIdx.x * 64;

  // Q A-fragments: lane holds q[m=lh][k=q4*8+j] (dh split in two k-steps of 32)
  const unsigned short* qrow = Q + (size_t)(b * 512 + q0 + w * 16 + lh) * 1024 + h * 64;
  bf16x8 aq0 = *(const bf16x8*)(qrow + q4 * 8);
  bf16x8 aq1 = *(const bf16x8*)(qrow + 32 + q4 * 8);

  const float* brow = bias + (size_t)b * 4096;
  unsigned short* pbase = lds + 8192 + w * 1024;

  float mrow[4], lrow[4];
  f32x4 oa[4] = {};
#pragma unroll
  for (int e = 0; e < 4; ++e) { mrow[e] = -INFINITY; lrow[e] = 0.f; }

  for (int kt = 0; kt < 4096; kt += 64) {
    __syncthreads();   // previous iteration's LDS reads complete
#pragma unroll
    for (int i = 0; i < 2; ++i) {
      int c = w * 2 + i;
      int u = c * 512 + lane * 8;              // ushort linear index in 4096-ushort tile
      int th = u >> 11;                        // k-half (0/1)
      int rem = u & 2047;
      int rrow = rem >> 5;                     // row within [64][32]
      int kin = rem & 31;
      // K tile: rows = tokens, cols = dh (split halves)
      cp16(Kp + (size_t)(b * 4096 + kt + rrow) * 1024 + h * 64 + th * 32 + kin,
           lds + c * 512);
      // VT tile: rows = dh cols of head, cols = tokens (split halves)
      cp16(VT + (size_t)(h * 64 + rrow) * 16384 + b * 4096 + kt + th * 32 + kin,
           lds + 4096 + c * 512);
    }
    __syncthreads();   // staging visible

    // S strip (16 q-rows x 64 tokens): col tiles c of 16 tokens
    f32x4 s[4];
#pragma unroll
    for (int c = 0; c < 4; ++c) {
      bf16x8 bk0 = *(const bf16x8*)(lds + (c * 16 + lh) * 32 + q4 * 8);
      bf16x8 bk1 = *(const bf16x8*)(lds + 2048 + (c * 16 + lh) * 32 + q4 * 8);
      f32x4 z = {};
      z = __builtin_amdgcn_mfma_f32_16x16x32_bf16(aq0, bk0, z, 0, 0, 0);
      z = __builtin_amdgcn_mfma_f32_16x16x32_bf16(aq1, bk1, z, 0, 0, 0);
      float bb = brow[kt + c * 16 + lh];       // bias per key col
#pragma unroll
      for (int e = 0; e < 4; ++e) z[e] += bb;
      s[c] = z;
    }

    // online softmax per row (row = q4*4+e); reduce across 16 lanes sharing q4
    float alpha[4];
#pragma unroll
    for (int e = 0; e < 4; ++e) {
      float mx = fmaxf(fmaxf(s[0][e], s[1][e]), fmaxf(s[2][e], s[3][e]));
      mx = fmaxf(mx, __shfl_xor(mx, 1, 16));
      mx = fmaxf(mx, __shfl_xor(mx, 2, 16));
      mx = fmaxf(mx, __shfl_xor(mx, 4, 16));
      mx = fmaxf(mx, __shfl_xor(mx, 8, 16));
      float mnew = fmaxf(mrow[e], mx);
      float a_ = __expf(mrow[e] - mnew);
      float rs = 0.f;
#pragma unroll
      for (int c = 0; c < 4; ++c) { float p = __expf(s[c][e] - mnew); s[c][e] = p; rs += p; }
      rs += __shfl_xor(rs, 1, 16);
      rs += __shfl_xor(rs, 2, 16);
      rs += __shfl_xor(rs, 4, 16);
      rs += __shfl_xor(rs, 8, 16);
      lrow[e] = lrow[e] * a_ + rs;
      mrow[e] = mnew;
      alpha[e] = a_;
    }
#pragma unroll
    for (int c2 = 0; c2 < 4; ++c2)
#pragma unroll
      for (int e = 0; e < 4; ++e) oa[c2][e] *= alpha[e];

    // P (C-layout) -> LDS [2][16][32] so it can be re-read in A-layout
#pragma unroll
    for (int c = 0; c < 4; ++c)
#pragma unroll
      for (int e = 0; e < 4; ++e)
        pbase[(c >> 1) * 512 + (q4 * 4 + e) * 32 + (c & 1) * 16 + lh] = f2bf(s[c][e]);
    __syncthreads();   // P visible (cross-lane), VT still valid

    // O strip += P(16x64) * V(64x64): A = P A-layout, B = VT rows
    bf16x8 ap0 = *(const bf16x8*)(pbase + lh * 32 + q4 * 8);
    bf16x8 ap1 = *(const bf16x8*)(pbase + 512 + lh * 32 + q4 * 8);
#pragma unroll
    for (int c2 = 0; c2 < 4; ++c2) {
      bf16x8 bv0 = *(const bf16x8*)(lds + 4096 + (c2 * 16 + lh) * 32 + q4 * 8);
      bf16x8 bv1 = *(const bf16x8*)(lds + 4096 + 2048 + (c2 * 16 + lh) * 32 + q4 * 8);
      oa[c2] = __builtin_amdgcn_mfma_f32_16x16x32_bf16(ap0, bv0, oa[c2], 0, 0, 0);
      oa[c2] = __builtin_amdgcn_mfma_f32_16x16x32_bf16(ap1, bv1, oa[c2], 0, 0, 0);
    }
  }

  // normalize and store
  unsigned short* orow = O + (size_t)(b * 512 + q0 + w * 16) * 1024 + h * 64;
#pragma unroll
  for (int c2 = 0; c2 < 4; ++c2)
#pragma unroll
    for (int e = 0; e < 4; ++e)
      orow[(size_t)(q4 * 4 + e) * 1024 + c2 * 16 + lh] = f2bf(oa[c2][e] / lrow[e]);
}

// ---------- launch ----------
extern "C" void kernel_launch(void* const* d_in, const int* in_sizes, int n_in,
                              void* d_out, int out_size, void* d_ws, size_t ws_size,
                              hipStream_t stream) {
  const float* query  = (const float*)d_in[0];  // [4,512,1024]
  const float* memory = (const float*)d_in[1];  // [4,4096,1024]
  const float* bias   = (const float*)d_in[2];  // [4,4096]
  const float* Wq     = (const float*)d_in[3];
  const float* Wk     = (const float*)d_in[4];
  const float* Wv     = (const float*)d_in[5];
  const float* Wo     = (const float*)d_in[6];
  float* out = (float*)d_out;

  unsigned short* ws  = (unsigned short*)d_ws;
  unsigned short* qbf = ws;                       // 2048*1024
  unsigned short* mbf = qbf + 2097152;            // 16384*1024
  unsigned short* WqT = mbf + 16777216;           // 1024*1024
  unsigned short* WkT = WqT + 1048576;
  unsigned short* WvT = WkT + 1048576;
  unsigned short* WoT = WvT + 1048576;
  unsigned short* qp  = WoT + 1048576;            // 2048*1024 (scaled q proj)
  unsigned short* kp  = qp + 2097152;             // 16384*1024
  unsigned short* vT  = kp + 16777216;            // 1024*16384 (v transposed)
  unsigned short* ao  = vT + 16777216;            // 2048*1024 (attn out)

  conv_bf16<<<2048, 256, 0, stream>>>(query, qbf, 524288);
  conv_bf16<<<16384, 256, 0, stream>>>(memory, mbf, 4194304);
  dim3 tb(32, 8);
  transpose_conv<<<dim3(32, 32), tb, 0, stream>>>(Wq, WqT);
  transpose_conv<<<dim3(32, 32), tb, 0, stream>>>(Wk, WkT);
  transpose_conv<<<dim3(32, 32), tb, 0, stream>>>(Wv, WvT);
  transpose_conv<<<dim3(32, 32), tb, 0, stream>>>(Wo, WoT);

  // q = (query@Wq) * 1/8   [2048 x 1024]
  gemm_bt<<<dim3(8, 16), 256, 0, stream>>>(qbf, WqT, nullptr, qp, 2048, 1024, 1024, 0.125f);
  // k = memory@Wk          [16384 x 1024]
  gemm_bt<<<dim3(8, 128), 256, 0, stream>>>(mbf, WkT, nullptr, kp, 16384, 1024, 1024, 1.f);
  // vT = Wv^T @ memory^T   [1024 x 16384]  (gemm_bt with A=WvT, B^T=mbf)
  gemm_bt<<<dim3(128, 8), 256, 0, stream>>>(WvT, mbf, nullptr, vT, 1024, 16384, 1024, 1.f);

  attn_kernel<<<dim3(8, 64), 256, 0, stream>>>(qp, kp, vT, bias, ao);

  // out = ao @ Wo  (fp32 out)
  gemm_bt<<<dim3(8, 16), 256, 0, stream>>>(ao, WoT, out, nullptr, 2048, 1024, 1024, 1.f);
}